// Round 22
// baseline (224.131 us; speedup 1.0000x reference)
//
#include <hip/hip_runtime.h>
#include <hip/hip_bf16.h>
#include <cstdint>

#define HW 50176
#define CB 96
#define BATCH 4
#define NTOK (BATCH*HW)
#define NWIN 4096
#define HIDDEN 384

typedef __attribute__((ext_vector_type(8))) short bf16x8;
typedef __attribute__((ext_vector_type(4))) short bf16x4;
typedef __attribute__((ext_vector_type(4))) float f32x4;

#define MFMA32(a,b,c) __builtin_amdgcn_mfma_f32_16x16x32_bf16(a,b,c,0,0,0)

#if __has_builtin(__builtin_amdgcn_mfma_f32_16x16x16bf16_1k)
#define MFMA16(a,b,c) __builtin_amdgcn_mfma_f32_16x16x16bf16_1k(a,b,c,0,0,0)
#elif __has_builtin(__builtin_amdgcn_mfma_f32_16x16x16_bf16)
#define MFMA16(a,b,c) __builtin_amdgcn_mfma_f32_16x16x16_bf16(a,b,c,0,0,0)
#else
static __device__ inline f32x4 mfma16_asm(bf16x4 a, bf16x4 b, f32x4 c){
  asm volatile("v_mfma_f32_16x16x16_bf16 %0, %1, %2, %0" : "+v"(c) : "v"(a), "v"(b));
  return c;
}
#define MFMA16(a,b,c) mfma16_asm(a,b,c)
#endif

#if __has_builtin(__builtin_amdgcn_rcpf)
#define FRCP(x) __builtin_amdgcn_rcpf(x)
#else
#define FRCP(x) (1.f/(x))
#endif
#if __has_builtin(__builtin_amdgcn_exp2f)
#define FEXP2(x) __builtin_amdgcn_exp2f(x)
#else
#define FEXP2(x) exp2f(x)
#endif

// scalar f32 -> bf16 via HW convert (RTNE)
__device__ inline unsigned short f2bf(float f){
  unsigned r;
  asm("v_cvt_pk_bf16_f32 %0, %1, %2" : "=v"(r) : "v"(f), "v"(f));
  return (unsigned short)r;
}
__device__ inline float bf2f(unsigned short h){
  union { unsigned u; float f; } x; x.u = ((unsigned)h) << 16; return x.f;
}
// packed bf16 pair via HW convert (gfx950 v_cvt_pk_bf16_f32)
__device__ inline unsigned pack2(float a, float b){
  unsigned r;
  asm("v_cvt_pk_bf16_f32 %0, %1, %2" : "=v"(r) : "v"(a), "v"(b));
  return r;
}

// sigmoid-GELU: v * sigmoid(1.702 v) = v * rcp(1 + exp2(-2.4555 v))
__device__ inline float gelu_sig(float v){
  float e = FEXP2(v * -2.4554572f);       // 1.702 * log2(e)
  float r = FRCP(e + 1.f);
  return v * r;
}

// ---------------- fused weight/bias prep (one launch) ----------------------
// w2P is packed N-MAJOR: ((n*6+co)*64+lane)*4+e  so each hidden-half
// (n in [12h,12h+12)) is a contiguous 36 KB slab for mlp's half-staging.
__global__ __launch_bounds__(256) void prep_all(
    const float* __restrict__ qkv_w, const float* __restrict__ proj_w,
    const float* __restrict__ w1, const float* __restrict__ w2,
    const float* __restrict__ rb, const int* __restrict__ ri,
    unsigned short* __restrict__ qkvT, unsigned short* __restrict__ projT,
    unsigned short* __restrict__ w1P, unsigned short* __restrict__ w2P,
    float* __restrict__ biasT){
  int b = blockIdx.x;
  if (b < 108){
    int id = b * 256 + threadIdx.x;                    // 27648
    int n = id / 96, k = id - n * 96;
    qkvT[id] = f2bf(qkv_w[k * 288 + n]);
  } else if (b < 144){
    int id = (b - 108) * 256 + threadIdx.x;            // 9216
    int n = id / 96, k = id - n * 96;
    projT[id] = f2bf(proj_w[k * 96 + n]);
  } else if (b < 288){
    int t = (b - 144) * 256 + threadIdx.x;             // 36864
    int e = t & 7, lane = (t >> 3) & 63, rest = t >> 9;
    int ks = rest % 3, n = rest / 3;
    int k = ks * 32 + (lane >> 4) * 8 + e;
    int o = n * 16 + (lane & 15);
    w1P[t] = f2bf(w1[k * HIDDEN + o]);
  } else if (b < 432){
    int t = (b - 288) * 256 + threadIdx.x;             // 36864
    int e = t & 3, l = (t >> 2) & 63, rest = t >> 8;
    int co = rest % 6, n = rest / 6;                   // n-major
    int k = 16 * n + 4 * (l >> 4) + e;
    int c = 16 * co + (l & 15);
    w2P[t] = f2bf(w2[k * CB + c]);
  } else {
    int t = (b - 432) * 256 + threadIdx.x;             // 12288
    int h = t >> 12, k = (t >> 6) & 63, q = t & 63;
    float v = 0.f;
    if (k < 49 && q < 49) v = rb[ri[q * 49 + k] * 3 + h];
    biasT[((h * 16 + (k >> 2)) * 64 + q) * 4 + (k & 3)] = v;
  }
}

// ---------------- LN1: NCHW -> token-major bf16, layernorm over C ----------
__global__ __launch_bounds__(256) void ln_first(const float* __restrict__ x,
    const float* __restrict__ g, const float* __restrict__ bta,
    unsigned short* __restrict__ out){
  __shared__ float s[64][97];
  int tid = threadIdx.x;
  int blk = blockIdx.x;
  int bi = blk / (HW / 64);
  int pos0 = (blk - bi * (HW / 64)) * 64;
  const float* xb = x + (size_t)bi * CB * HW + pos0;
  for (int it = 0; it < 24; ++it){
    int idx = it * 256 + tid;
    int c = idx >> 6, p = idx & 63;
    s[p][c] = xb[(size_t)c * HW + p];
  }
  __syncthreads();
  int p = tid >> 2, part = tid & 3;
  float sum = 0.f, sq = 0.f;
  #pragma unroll
  for (int j = 0; j < 24; ++j){ float v = s[p][part * 24 + j]; sum += v; sq += v * v; }
  sum += __shfl_xor(sum, 1); sq += __shfl_xor(sq, 1);
  sum += __shfl_xor(sum, 2); sq += __shfl_xor(sq, 2);
  float mean = sum * (1.f / 96.f);
  float var  = sq * (1.f / 96.f) - mean * mean;
  float rs = rsqrtf(var + 1e-5f);
  size_t tok = (size_t)bi * HW + pos0 + p;
  float vv[24];
  #pragma unroll
  for (int j = 0; j < 24; ++j){
    int c = part * 24 + j;
    vv[j] = (s[p][c] - mean) * rs * g[c] + bta[c];
  }
  unsigned pw[12];
  #pragma unroll
  for (int j = 0; j < 12; ++j) pw[j] = pack2(vv[2 * j], vv[2 * j + 1]);
  uint4* dst = (uint4*)(out + tok * CB + part * 24);
  dst[0] = make_uint4(pw[0], pw[1], pw[2], pw[3]);
  dst[1] = make_uint4(pw[4], pw[5], pw[6], pw[7]);
  dst[2] = make_uint4(pw[8], pw[9], pw[10], pw[11]);
}

// ---------------- fused qkv-GEMM + MFMA window attention (in-place xn) -----
__global__ __launch_bounds__(256) void attn_fused(
    unsigned short* __restrict__ xn,           // in: xn1, out: attn_out
    const unsigned short* __restrict__ qkvT,   // (288,96) bf16
    const float* __restrict__ qkv_b,
    const float* __restrict__ biasT){          // [3][16][64][4] fp32
  __shared__ unsigned short sQ[64][104];
  __shared__ unsigned short sK[64][104];
  __shared__ unsigned short sVT[3][32][72];
  __shared__ unsigned short sP[64][72];
  int tid = threadIdx.x;
  int wid = blockIdx.x;
  int bi = wid >> 10;
  int wy = (wid & 1023) >> 5, wx = wid & 31;
  int rowbase = bi * HW + (wy * 7) * 224 + wx * 7;

  int wv = tid >> 6, lane = tid & 63;
  int r = lane & 15, g = lane >> 4;
  int kg = g * 8;
  int nbase = (wv < 2) ? wv * 5 : 10 + (wv - 2) * 4;
  int ncnt  = (wv < 2) ? 5 : 4;
  int arow[4];
  #pragma unroll
  for (int m = 0; m < 4; ++m){
    int rr = m * 16 + r; if (rr > 48) rr = 48;
    arow[m] = rowbase + (rr / 7) * 224 + (rr % 7);
  }
  f32x4 acc[4][5];
  #pragma unroll
  for (int m = 0; m < 4; ++m)
    #pragma unroll
    for (int j = 0; j < 5; ++j) acc[m][j] = (f32x4){0.f,0.f,0.f,0.f};
  #pragma unroll
  for (int k0 = 0; k0 < 96; k0 += 32){
    bf16x8 a[4];
    #pragma unroll
    for (int m = 0; m < 4; ++m)
      a[m] = *(const bf16x8*)(xn + (size_t)arow[m] * CB + kg + k0);
    #pragma unroll
    for (int j = 0; j < 5; ++j){
      if (j < ncnt){
        int nt = nbase + j;
        bf16x8 b = *(const bf16x8*)(qkvT + (nt * 16 + r) * CB + kg + k0);
        #pragma unroll
        for (int m = 0; m < 4; ++m)
          acc[m][j] = MFMA32(a[m], b, acc[m][j]);
      }
    }
  }
  int orow = g * 4;
  #pragma unroll
  for (int j = 0; j < 5; ++j){
    if (j < ncnt){
      int nt = nbase + j;
      int col = nt * 16 + r;
      float bs = qkv_b[col];
      #pragma unroll
      for (int m = 0; m < 4; ++m){
        #pragma unroll
        for (int i = 0; i < 4; ++i){
          int row = m * 16 + orow + i;
          float v = (row < 49) ? acc[m][j][i] + bs : 0.f;
          if (col < 96)       sQ[row][col] = f2bf(v * 0.17677669529663687f);
          else if (col < 192) sK[row][col - 96] = f2bf(v);
          else { int cc = col - 192; sVT[cc >> 5][cc & 31][row] = f2bf(v); }
        }
      }
    }
  }
  __syncthreads();

  int qrow = 16 * wv + r;
  int qq = 16 * wv + 4 * g;
  int tokO[4];
  #pragma unroll
  for (int i = 0; i < 4; ++i){
    int q = qq + i;
    tokO[i] = rowbase + (q / 7) * 224 + (q % 7);
  }
  #pragma unroll
  for (int h = 0; h < 3; ++h){
    bf16x8 bq = *(const bf16x8*)&sQ[qrow][h * 32 + kg];
    f32x4 sacc[4];
    #pragma unroll
    for (int j = 0; j < 4; ++j)
      sacc[j] = *(const f32x4*)&biasT[(((h * 16) + 4 * j + g) * 64 + qrow) * 4];
    __builtin_amdgcn_s_setprio(1);
    #pragma unroll
    for (int j = 0; j < 4; ++j){
      bf16x8 ak = *(const bf16x8*)&sK[16 * j + r][h * 32 + kg];
      sacc[j] = MFMA32(ak, bq, sacc[j]);
    }
    __builtin_amdgcn_s_setprio(0);
    float mx = -1e30f;
    #pragma unroll
    for (int j = 0; j < 4; ++j)
      #pragma unroll
      for (int i = 0; i < 4; ++i){
        int k = 16 * j + 4 * g + i;
        if (k <= 48) mx = fmaxf(mx, sacc[j][i]);
      }
    mx = fmaxf(mx, __shfl_xor(mx, 16));
    mx = fmaxf(mx, __shfl_xor(mx, 32));
    float p[4][4], sum = 0.f;
    #pragma unroll
    for (int j = 0; j < 4; ++j)
      #pragma unroll
      for (int i = 0; i < 4; ++i){
        int k = 16 * j + 4 * g + i;
        float pv = (k <= 48) ? __expf(sacc[j][i] - mx) : 0.f;
        p[j][i] = pv; sum += pv;
      }
    sum += __shfl_xor(sum, 16);
    sum += __shfl_xor(sum, 32);
    float inv = FRCP(sum);
    #pragma unroll
    for (int j = 0; j < 4; ++j){
      uint2 w2;
      w2.x = pack2(p[j][0] * inv, p[j][1] * inv);
      w2.y = pack2(p[j][2] * inv, p[j][3] * inv);
      *(uint2*)&sP[qrow][16 * j + 4 * g] = w2;
    }
    // no barrier: sP rows are wave-private
    f32x4 oacc[2];
    oacc[0] = (f32x4){0.f,0.f,0.f,0.f};
    oacc[1] = (f32x4){0.f,0.f,0.f,0.f};
    __builtin_amdgcn_s_setprio(1);
    #pragma unroll
    for (int k0 = 0; k0 < 64; k0 += 32){
      bf16x8 ap = *(const bf16x8*)&sP[16 * wv + r][k0 + kg];
      #pragma unroll
      for (int n = 0; n < 2; ++n){
        bf16x8 bv = *(const bf16x8*)&sVT[h][n * 16 + r][k0 + kg];
        oacc[n] = MFMA32(ap, bv, oacc[n]);
      }
    }
    __builtin_amdgcn_s_setprio(0);
    #pragma unroll
    for (int i = 0; i < 4; ++i){
      if (qq + i < 49){
        unsigned short* dst = xn + (size_t)tokO[i] * CB + h * 32 + r;
        dst[0]  = f2bf(oacc[0][i]);
        dst[16] = f2bf(oacc[1][i]);
      }
    }
  }
}

// ---------------- proj GEMM + bias + residual -> x2 (bf16, in-place) -------
__global__ __launch_bounds__(256) void proj_res(
    unsigned short* __restrict__ att,          // in: attn_out, out: x2 (bf16)
    const unsigned short* __restrict__ projT, const float* __restrict__ proj_b,
    const float* __restrict__ x){
  int tid = threadIdx.x, blk = blockIdx.x;
  int bi = blk / (HW / 64);
  int pos0 = (blk - bi * (HW / 64)) * 64;
  int wv = tid >> 6, lane = tid & 63, r = lane & 15, g = lane >> 4;
  int pos = pos0 + wv * 16 + r;
  size_t tok = (size_t)bi * HW + pos;

  bf16x8 ab[3];
  #pragma unroll
  for (int ks = 0; ks < 3; ++ks)
    ab[ks] = *(const bf16x8*)(att + tok * CB + ks * 32 + g * 8);
  f32x4 acc[6];
  #pragma unroll
  for (int co = 0; co < 6; ++co) acc[co] = (f32x4){0.f,0.f,0.f,0.f};
  #pragma unroll
  for (int ks = 0; ks < 3; ++ks){
    #pragma unroll
    for (int co = 0; co < 6; ++co){
      bf16x8 a = *(const bf16x8*)(projT + (co * 16 + r) * CB + ks * 32 + g * 8);
      acc[co] = MFMA32(a, ab[ks], acc[co]);
    }
  }
  const float* xb = x + (size_t)bi * CB * HW + pos;
  #pragma unroll
  for (int co = 0; co < 6; ++co){
    float4 bv = *(const float4*)&proj_b[co * 16 + 4 * g];
    float bb[4] = {bv.x, bv.y, bv.z, bv.w};
    float y[4];
    #pragma unroll
    for (int i = 0; i < 4; ++i){
      int c = co * 16 + 4 * g + i;
      y[i] = acc[co][i] + bb[i] + xb[(size_t)c * HW];
    }
    uint2 w2 = make_uint2(pack2(y[0], y[1]), pack2(y[2], y[3]));
    *(uint2*)(att + tok * CB + co * 16 + 4 * g) = w2;
  }
}

// ---------------- fused MLP v19: sequential hidden-halves, 73.7 KB LDS -----
// block = 512 thr (8 waves) = 256 tokens. Hidden dim processed in TWO
// LDS-resident halves (192 each): stage half -> sync -> 12-n loop (v18 body)
// -> sync -> next half. acc2 persists across halves (same live set as v18's
// 24-n loop). LDS 73728 B -> 2 blocks/CU = 4 waves/SIMD (was 2).
__global__ __launch_bounds__(512) void mlp_fused(
    const unsigned short* __restrict__ x2b,    // x2 bf16 token-major (att buf)
    const unsigned short* __restrict__ wP,     // w1P (36864) ++ w2P (36864, n-major)
    const float* __restrict__ b1, const float* __restrict__ b2,
    const float* __restrict__ gam, const float* __restrict__ bet,
    float* __restrict__ io){                   // d_out, write-only
  __shared__ unsigned short sW[36864];         // 73728 B: [0,18432)=w1 half, [18432,36864)=w2 half
  int tid = threadIdx.x, blk = blockIdx.x;
  int bi = blk / (HW / 256);
  int pos0 = (blk - bi * (HW / 256)) * 256;

  int wv = tid >> 6, lane = tid & 63, r = lane & 15, g = lane >> 4;
  int pos = pos0 + wv * 32 + r;                // group m adds m*16
  size_t tok = (size_t)bi * HW + pos;

  // ---- load x2 frags + inline LN2 -> xn2 fragments xb[2][3] ----
  bf16x8 xb[2][3];
  #pragma unroll
  for (int m = 0; m < 2; ++m){
    bf16x8 xc[3];
    float xv[24];
    float sum = 0.f, sq = 0.f;
    #pragma unroll
    for (int ks = 0; ks < 3; ++ks){
      xc[ks] = *(const bf16x8*)(x2b + (tok + m * 16) * CB + ks * 32 + g * 8);
      #pragma unroll
      for (int e = 0; e < 8; ++e){
        float v = bf2f((unsigned short)xc[ks][e]);
        xv[ks * 8 + e] = v;
        sum += v; sq += v * v;
      }
    }
    sum += __shfl_xor(sum, 16); sq += __shfl_xor(sq, 16);
    sum += __shfl_xor(sum, 32); sq += __shfl_xor(sq, 32);
    float mean = sum * (1.f / 96.f);
    float var  = sq * (1.f / 96.f) - mean * mean;
    float rs = rsqrtf(var + 1e-5f);
    #pragma unroll
    for (int ks = 0; ks < 3; ++ks){
      float4 g0 = *(const float4*)&gam[ks * 32 + g * 8];
      float4 g1 = *(const float4*)&gam[ks * 32 + g * 8 + 4];
      float4 b0 = *(const float4*)&bet[ks * 32 + g * 8];
      float4 b1v = *(const float4*)&bet[ks * 32 + g * 8 + 4];
      float gg[8] = {g0.x,g0.y,g0.z,g0.w,g1.x,g1.y,g1.z,g1.w};
      float bb[8] = {b0.x,b0.y,b0.z,b0.w,b1v.x,b1v.y,b1v.z,b1v.w};
      unsigned pw[4];
      #pragma unroll
      for (int e2 = 0; e2 < 4; ++e2){
        float v0 = (xv[ks * 8 + 2*e2]   - mean) * rs * gg[2*e2]   + bb[2*e2];
        float v1 = (xv[ks * 8 + 2*e2+1] - mean) * rs * gg[2*e2+1] + bb[2*e2+1];
        pw[e2] = pack2(v0, v1);
      }
      union { unsigned u[4]; bf16x8 v; } u;
      u.u[0] = pw[0]; u.u[1] = pw[1]; u.u[2] = pw[2]; u.u[3] = pw[3];
      xb[m][ks] = u.v;
    }
  }

  f32x4 acc2[2][6];
  #pragma unroll
  for (int m = 0; m < 2; ++m)
    #pragma unroll
    for (int co = 0; co < 6; ++co) acc2[m][co] = (f32x4){0.f,0.f,0.f,0.f};

  #pragma unroll 1
  for (int h2 = 0; h2 < 2; ++h2){
    // ---- stage half h2: w1 slab + w2 slab (each 18432 shorts) ----
    const unsigned short* src1 = wP + h2 * 18432;
    const unsigned short* src2 = wP + 36864 + h2 * 18432;
    #pragma unroll
    for (int it = 0; it < 9; ++it){
      int idx = it * 512 + tid;                // 4608 uint4 chunks
      const unsigned short* s = (idx < 2304) ? (src1 + (size_t)idx * 8)
                                             : (src2 + (size_t)(idx - 2304) * 8);
      *(uint4*)&sW[idx * 8] = *(const uint4*)s;
    }
    __syncthreads();

    const float* b1h = b1 + h2 * 192;
    #pragma unroll
    for (int nl = 0; nl < 12; ++nl){
      f32x4 acc0 = (f32x4){0.f,0.f,0.f,0.f};
      f32x4 acc1 = (f32x4){0.f,0.f,0.f,0.f};
      __builtin_amdgcn_s_setprio(1);
      #pragma unroll
      for (int ks = 0; ks < 3; ++ks){
        bf16x8 a = *(const bf16x8*)&sW[((nl * 3 + ks) * 64 + lane) * 8];
        acc0 = MFMA32(a, xb[0][ks], acc0);
        acc1 = MFMA32(a, xb[1][ks], acc1);
      }
      __builtin_amdgcn_s_setprio(0);
      float4 bv = *(const float4*)&b1h[nl * 16 + 4 * g];
      union { unsigned u[2]; bf16x4 v; } u0, u1;
      u0.u[0] = pack2(gelu_sig(acc0[0] + bv.x), gelu_sig(acc0[1] + bv.y));
      u0.u[1] = pack2(gelu_sig(acc0[2] + bv.z), gelu_sig(acc0[3] + bv.w));
      u1.u[0] = pack2(gelu_sig(acc1[0] + bv.x), gelu_sig(acc1[1] + bv.y));
      u1.u[1] = pack2(gelu_sig(acc1[2] + bv.z), gelu_sig(acc1[3] + bv.w));
      bf16x4 h0 = u0.v, h1 = u1.v;
      __builtin_amdgcn_s_setprio(1);
      #pragma unroll
      for (int co = 0; co < 6; ++co){
        bf16x4 a2 = *(const bf16x4*)&sW[18432 + ((nl * 6 + co) * 64 + lane) * 4];
        acc2[0][co] = MFMA16(a2, h0, acc2[0][co]);
        acc2[1][co] = MFMA16(a2, h1, acc2[1][co]);
      }
      __builtin_amdgcn_s_setprio(0);
    }
    __syncthreads();                           // all reads done before restage
  }

  // ---- epilogue: out = x2 + y + b2, write-only NCHW ----
  #pragma unroll
  for (int co = 0; co < 6; ++co){
    float4 bv = *(const float4*)&b2[co * 16 + 4 * g];
    float bb[4] = {bv.x, bv.y, bv.z, bv.w};
    #pragma unroll
    for (int i = 0; i < 4; ++i){
      int c = co * 16 + 4 * g + i;
      float* p0 = io + ((size_t)bi * CB + c) * HW + pos;
      #pragma unroll
      for (int m = 0; m < 2; ++m){
        float x2s = bf2f(x2b[(tok + m * 16) * CB + c]);
        p0[m * 16] = x2s + acc2[m][co][i] + bb[i];
      }
    }
  }
}

extern "C" void kernel_launch(void* const* d_in, const int* in_sizes, int n_in,
                              void* d_out, int out_size, void* d_ws, size_t ws_size,
                              hipStream_t stream){
  const float* x        = (const float*)d_in[0];
  const float* n1g      = (const float*)d_in[1];
  const float* n1b      = (const float*)d_in[2];
  const float* qkv_w    = (const float*)d_in[3];
  const float* qkv_b    = (const float*)d_in[4];
  const float* proj_w   = (const float*)d_in[5];
  const float* proj_b   = (const float*)d_in[6];
  const float* rel_bias = (const float*)d_in[7];
  const float* n2g      = (const float*)d_in[8];
  const float* n2b      = (const float*)d_in[9];
  const float* w1       = (const float*)d_in[10];
  const float* b1       = (const float*)d_in[11];
  const float* w2       = (const float*)d_in[12];
  const float* b2       = (const float*)d_in[13];
  const int* rel_index  = (const int*)d_in[14];
  float* outp = (float*)d_out;

  char* ws = (char*)d_ws;
  unsigned short* qkvT  = (unsigned short*)ws;            // 288x96 = 27648
  unsigned short* projT = qkvT + 288 * 96;                // 96x96 = 9216
  unsigned short* w1P   = projT + 96 * 96;                // packed 36864
  unsigned short* w2P   = w1P + 36864;                    // packed 36864 (n-major)
  float* biasT          = (float*)(ws + 221184);          // [3][16][64][4]
  unsigned short* xn    = (unsigned short*)(ws + 221184 + 49152);

  prep_all<<<dim3(480), 256, 0, stream>>>(qkv_w, proj_w, w1, w2, rel_bias,
                                          rel_index, qkvT, projT, w1P, w2P, biasT);

  ln_first  <<<dim3(NTOK / 64), 256, 0, stream>>>(x, n1g, n1b, xn);
  attn_fused<<<dim3(NWIN),      256, 0, stream>>>(xn, qkvT, qkv_b, biasT);
  proj_res  <<<dim3(NTOK / 64), 256, 0, stream>>>(xn, projT, proj_b, x);
  mlp_fused <<<dim3(NTOK / 256), 512, 0, stream>>>(xn, w1P, b1, b2, n2g, n2b, outp);
}

// Round 23
// 220.296 us; speedup vs baseline: 1.0174x; 1.0174x over previous
//
#include <hip/hip_runtime.h>
#include <hip/hip_bf16.h>
#include <cstdint>

#define HW 50176
#define CB 96
#define BATCH 4
#define NTOK (BATCH*HW)
#define NWIN 4096
#define HIDDEN 384

typedef __attribute__((ext_vector_type(8))) short bf16x8;
typedef __attribute__((ext_vector_type(4))) short bf16x4;
typedef __attribute__((ext_vector_type(4))) float f32x4;

#define MFMA32(a,b,c) __builtin_amdgcn_mfma_f32_16x16x32_bf16(a,b,c,0,0,0)

#if __has_builtin(__builtin_amdgcn_mfma_f32_16x16x16bf16_1k)
#define MFMA16(a,b,c) __builtin_amdgcn_mfma_f32_16x16x16bf16_1k(a,b,c,0,0,0)
#elif __has_builtin(__builtin_amdgcn_mfma_f32_16x16x16_bf16)
#define MFMA16(a,b,c) __builtin_amdgcn_mfma_f32_16x16x16_bf16(a,b,c,0,0,0)
#else
static __device__ inline f32x4 mfma16_asm(bf16x4 a, bf16x4 b, f32x4 c){
  asm volatile("v_mfma_f32_16x16x16_bf16 %0, %1, %2, %0" : "+v"(c) : "v"(a), "v"(b));
  return c;
}
#define MFMA16(a,b,c) mfma16_asm(a,b,c)
#endif

#if __has_builtin(__builtin_amdgcn_rcpf)
#define FRCP(x) __builtin_amdgcn_rcpf(x)
#else
#define FRCP(x) (1.f/(x))
#endif
#if __has_builtin(__builtin_amdgcn_exp2f)
#define FEXP2(x) __builtin_amdgcn_exp2f(x)
#else
#define FEXP2(x) exp2f(x)
#endif

// scalar f32 -> bf16 via HW convert (RTNE)
__device__ inline unsigned short f2bf(float f){
  unsigned r;
  asm("v_cvt_pk_bf16_f32 %0, %1, %2" : "=v"(r) : "v"(f), "v"(f));
  return (unsigned short)r;
}
__device__ inline float bf2f(unsigned short h){
  union { unsigned u; float f; } x; x.u = ((unsigned)h) << 16; return x.f;
}
// packed bf16 pair via HW convert (gfx950 v_cvt_pk_bf16_f32)
__device__ inline unsigned pack2(float a, float b){
  unsigned r;
  asm("v_cvt_pk_bf16_f32 %0, %1, %2" : "=v"(r) : "v"(a), "v"(b));
  return r;
}

// sigmoid-GELU: v * sigmoid(1.702 v) = v * rcp(1 + exp2(-2.4555 v))
__device__ inline float gelu_sig(float v){
  float e = FEXP2(v * -2.4554572f);       // 1.702 * log2(e)
  float r = FRCP(e + 1.f);
  return v * r;
}

// ---------------- fused weight/bias prep (one launch) ----------------------
__global__ __launch_bounds__(256) void prep_all(
    const float* __restrict__ qkv_w, const float* __restrict__ proj_w,
    const float* __restrict__ w1, const float* __restrict__ w2,
    const float* __restrict__ rb, const int* __restrict__ ri,
    unsigned short* __restrict__ qkvT, unsigned short* __restrict__ projT,
    unsigned short* __restrict__ w1P, unsigned short* __restrict__ w2P,
    float* __restrict__ biasT){
  int b = blockIdx.x;
  if (b < 108){
    int id = b * 256 + threadIdx.x;                    // 27648
    int n = id / 96, k = id - n * 96;
    qkvT[id] = f2bf(qkv_w[k * 288 + n]);
  } else if (b < 144){
    int id = (b - 108) * 256 + threadIdx.x;            // 9216
    int n = id / 96, k = id - n * 96;
    projT[id] = f2bf(proj_w[k * 96 + n]);
  } else if (b < 288){
    int t = (b - 144) * 256 + threadIdx.x;             // 36864
    int e = t & 7, lane = (t >> 3) & 63, rest = t >> 9;
    int ks = rest % 3, n = rest / 3;
    int k = ks * 32 + (lane >> 4) * 8 + e;
    int o = n * 16 + (lane & 15);
    w1P[t] = f2bf(w1[k * HIDDEN + o]);
  } else if (b < 432){
    int t = (b - 288) * 256 + threadIdx.x;             // 36864
    int e = t & 3, l = (t >> 2) & 63, rest = t >> 8;
    int n = rest % 24, co = rest / 24;
    int k = 16 * n + 4 * (l >> 4) + e;
    int c = 16 * co + (l & 15);
    w2P[t] = f2bf(w2[k * CB + c]);
  } else {
    int t = (b - 432) * 256 + threadIdx.x;             // 12288
    int h = t >> 12, k = (t >> 6) & 63, q = t & 63;
    float v = 0.f;
    if (k < 49 && q < 49) v = rb[ri[q * 49 + k] * 3 + h];
    biasT[((h * 16 + (k >> 2)) * 64 + q) * 4 + (k & 3)] = v;
  }
}

// ---------------- LN1: NCHW -> token-major bf16, layernorm over C ----------
__global__ __launch_bounds__(256) void ln_first(const float* __restrict__ x,
    const float* __restrict__ g, const float* __restrict__ bta,
    unsigned short* __restrict__ out){
  __shared__ float s[64][97];
  int tid = threadIdx.x;
  int blk = blockIdx.x;
  int bi = blk / (HW / 64);
  int pos0 = (blk - bi * (HW / 64)) * 64;
  const float* xb = x + (size_t)bi * CB * HW + pos0;
  for (int it = 0; it < 24; ++it){
    int idx = it * 256 + tid;
    int c = idx >> 6, p = idx & 63;
    s[p][c] = xb[(size_t)c * HW + p];
  }
  __syncthreads();
  int p = tid >> 2, part = tid & 3;
  float sum = 0.f, sq = 0.f;
  #pragma unroll
  for (int j = 0; j < 24; ++j){ float v = s[p][part * 24 + j]; sum += v; sq += v * v; }
  sum += __shfl_xor(sum, 1); sq += __shfl_xor(sq, 1);
  sum += __shfl_xor(sum, 2); sq += __shfl_xor(sq, 2);
  float mean = sum * (1.f / 96.f);
  float var  = sq * (1.f / 96.f) - mean * mean;
  float rs = rsqrtf(var + 1e-5f);
  size_t tok = (size_t)bi * HW + pos0 + p;
  float vv[24];
  #pragma unroll
  for (int j = 0; j < 24; ++j){
    int c = part * 24 + j;
    vv[j] = (s[p][c] - mean) * rs * g[c] + bta[c];
  }
  unsigned pw[12];
  #pragma unroll
  for (int j = 0; j < 12; ++j) pw[j] = pack2(vv[2 * j], vv[2 * j + 1]);
  uint4* dst = (uint4*)(out + tok * CB + part * 24);
  dst[0] = make_uint4(pw[0], pw[1], pw[2], pw[3]);
  dst[1] = make_uint4(pw[4], pw[5], pw[6], pw[7]);
  dst[2] = make_uint4(pw[8], pw[9], pw[10], pw[11]);
}

// ---------------- fused qkv-GEMM + MFMA window attention (in-place xn) -----
// ONE barrier total (sP rows are wave-private). No setprio in the qkv
// K-loop (code-motion fence serialized the 12 HBM A-loads).
__global__ __launch_bounds__(256) void attn_fused(
    unsigned short* __restrict__ xn,           // in: xn1, out: attn_out
    const unsigned short* __restrict__ qkvT,   // (288,96) bf16
    const float* __restrict__ qkv_b,
    const float* __restrict__ biasT){          // [3][16][64][4] fp32
  __shared__ unsigned short sQ[64][104];
  __shared__ unsigned short sK[64][104];
  __shared__ unsigned short sVT[3][32][72];
  __shared__ unsigned short sP[64][72];
  int tid = threadIdx.x;
  int wid = blockIdx.x;
  int bi = wid >> 10;
  int wy = (wid & 1023) >> 5, wx = wid & 31;
  int rowbase = bi * HW + (wy * 7) * 224 + wx * 7;

  int wv = tid >> 6, lane = tid & 63;
  int r = lane & 15, g = lane >> 4;
  int kg = g * 8;
  int nbase = (wv < 2) ? wv * 5 : 10 + (wv - 2) * 4;
  int ncnt  = (wv < 2) ? 5 : 4;
  int arow[4];
  #pragma unroll
  for (int m = 0; m < 4; ++m){
    int rr = m * 16 + r; if (rr > 48) rr = 48;
    arow[m] = rowbase + (rr / 7) * 224 + (rr % 7);
  }
  f32x4 acc[4][5];
  #pragma unroll
  for (int m = 0; m < 4; ++m)
    #pragma unroll
    for (int j = 0; j < 5; ++j) acc[m][j] = (f32x4){0.f,0.f,0.f,0.f};
  #pragma unroll
  for (int k0 = 0; k0 < 96; k0 += 32){
    bf16x8 a[4];
    #pragma unroll
    for (int m = 0; m < 4; ++m)
      a[m] = *(const bf16x8*)(xn + (size_t)arow[m] * CB + kg + k0);
    #pragma unroll
    for (int j = 0; j < 5; ++j){
      if (j < ncnt){
        int nt = nbase + j;
        bf16x8 b = *(const bf16x8*)(qkvT + (nt * 16 + r) * CB + kg + k0);
        #pragma unroll
        for (int m = 0; m < 4; ++m)
          acc[m][j] = MFMA32(a[m], b, acc[m][j]);
      }
    }
  }
  int orow = g * 4;
  #pragma unroll
  for (int j = 0; j < 5; ++j){
    if (j < ncnt){
      int nt = nbase + j;
      int col = nt * 16 + r;
      float bs = qkv_b[col];
      #pragma unroll
      for (int m = 0; m < 4; ++m){
        #pragma unroll
        for (int i = 0; i < 4; ++i){
          int row = m * 16 + orow + i;
          float v = (row < 49) ? acc[m][j][i] + bs : 0.f;
          if (col < 96)       sQ[row][col] = f2bf(v * 0.17677669529663687f);
          else if (col < 192) sK[row][col - 96] = f2bf(v);
          else { int cc = col - 192; sVT[cc >> 5][cc & 31][row] = f2bf(v); }
        }
      }
    }
  }
  __syncthreads();

  int qrow = 16 * wv + r;
  int qq = 16 * wv + 4 * g;
  int tokO[4];
  #pragma unroll
  for (int i = 0; i < 4; ++i){
    int q = qq + i;
    tokO[i] = rowbase + (q / 7) * 224 + (q % 7);
  }
  #pragma unroll
  for (int h = 0; h < 3; ++h){
    bf16x8 bq = *(const bf16x8*)&sQ[qrow][h * 32 + kg];
    f32x4 sacc[4];
    #pragma unroll
    for (int j = 0; j < 4; ++j)
      sacc[j] = *(const f32x4*)&biasT[(((h * 16) + 4 * j + g) * 64 + qrow) * 4];
    __builtin_amdgcn_s_setprio(1);
    #pragma unroll
    for (int j = 0; j < 4; ++j){
      bf16x8 ak = *(const bf16x8*)&sK[16 * j + r][h * 32 + kg];
      sacc[j] = MFMA32(ak, bq, sacc[j]);
    }
    __builtin_amdgcn_s_setprio(0);
    float mx = -1e30f;
    #pragma unroll
    for (int j = 0; j < 4; ++j)
      #pragma unroll
      for (int i = 0; i < 4; ++i){
        int k = 16 * j + 4 * g + i;
        if (k <= 48) mx = fmaxf(mx, sacc[j][i]);
      }
    mx = fmaxf(mx, __shfl_xor(mx, 16));
    mx = fmaxf(mx, __shfl_xor(mx, 32));
    float p[4][4], sum = 0.f;
    #pragma unroll
    for (int j = 0; j < 4; ++j)
      #pragma unroll
      for (int i = 0; i < 4; ++i){
        int k = 16 * j + 4 * g + i;
        float pv = (k <= 48) ? __expf(sacc[j][i] - mx) : 0.f;
        p[j][i] = pv; sum += pv;
      }
    sum += __shfl_xor(sum, 16);
    sum += __shfl_xor(sum, 32);
    float inv = FRCP(sum);
    #pragma unroll
    for (int j = 0; j < 4; ++j){
      uint2 w2;
      w2.x = pack2(p[j][0] * inv, p[j][1] * inv);
      w2.y = pack2(p[j][2] * inv, p[j][3] * inv);
      *(uint2*)&sP[qrow][16 * j + 4 * g] = w2;
    }
    // no barrier: sP rows are wave-private
    f32x4 oacc[2];
    oacc[0] = (f32x4){0.f,0.f,0.f,0.f};
    oacc[1] = (f32x4){0.f,0.f,0.f,0.f};
    __builtin_amdgcn_s_setprio(1);
    #pragma unroll
    for (int k0 = 0; k0 < 64; k0 += 32){
      bf16x8 ap = *(const bf16x8*)&sP[16 * wv + r][k0 + kg];
      #pragma unroll
      for (int n = 0; n < 2; ++n){
        bf16x8 bv = *(const bf16x8*)&sVT[h][n * 16 + r][k0 + kg];
        oacc[n] = MFMA32(ap, bv, oacc[n]);
      }
    }
    __builtin_amdgcn_s_setprio(0);
    #pragma unroll
    for (int i = 0; i < 4; ++i){
      if (qq + i < 49){
        unsigned short* dst = xn + (size_t)tokO[i] * CB + h * 32 + r;
        dst[0]  = f2bf(oacc[0][i]);
        dst[16] = f2bf(oacc[1][i]);
      }
    }
  }
}

// ---------------- proj GEMM + bias + residual -> x2 (bf16, in-place) -------
__global__ __launch_bounds__(256) void proj_res(
    unsigned short* __restrict__ att,          // in: attn_out, out: x2 (bf16)
    const unsigned short* __restrict__ projT, const float* __restrict__ proj_b,
    const float* __restrict__ x){
  int tid = threadIdx.x, blk = blockIdx.x;
  int bi = blk / (HW / 64);
  int pos0 = (blk - bi * (HW / 64)) * 64;
  int wv = tid >> 6, lane = tid & 63, r = lane & 15, g = lane >> 4;
  int pos = pos0 + wv * 16 + r;
  size_t tok = (size_t)bi * HW + pos;

  bf16x8 ab[3];
  #pragma unroll
  for (int ks = 0; ks < 3; ++ks)
    ab[ks] = *(const bf16x8*)(att + tok * CB + ks * 32 + g * 8);
  f32x4 acc[6];
  #pragma unroll
  for (int co = 0; co < 6; ++co) acc[co] = (f32x4){0.f,0.f,0.f,0.f};
  #pragma unroll
  for (int ks = 0; ks < 3; ++ks){
    #pragma unroll
    for (int co = 0; co < 6; ++co){
      bf16x8 a = *(const bf16x8*)(projT + (co * 16 + r) * CB + ks * 32 + g * 8);
      acc[co] = MFMA32(a, ab[ks], acc[co]);
    }
  }
  const float* xb = x + (size_t)bi * CB * HW + pos;
  #pragma unroll
  for (int co = 0; co < 6; ++co){
    float4 bv = *(const float4*)&proj_b[co * 16 + 4 * g];
    float bb[4] = {bv.x, bv.y, bv.z, bv.w};
    float y[4];
    #pragma unroll
    for (int i = 0; i < 4; ++i){
      int c = co * 16 + 4 * g + i;
      y[i] = acc[co][i] + bb[i] + xb[(size_t)c * HW];
    }
    uint2 w2 = make_uint2(pack2(y[0], y[1]), pack2(y[2], y[3]));
    *(uint2*)(att + tok * CB + co * 16 + 4 * g) = w2;
  }
}

// ---------------- fused MLP v18 (best measured): 147 KB LDS, cvt_pk --------
// block = 512 thr (8 waves) = 256 tokens; w1P+w2P stationary in LDS.
// VGPR 88, zero spill — the allocator's proven happy path. v19's 73.7 KB
// half-staging variant did NOT raise measured occupancy (17%) and cost 3%.
__global__ __launch_bounds__(512) void mlp_fused(
    const unsigned short* __restrict__ x2b,    // x2 bf16 token-major (att buf)
    const unsigned short* __restrict__ wP,     // w1P (36864) ++ w2P (36864)
    const float* __restrict__ b1, const float* __restrict__ b2,
    const float* __restrict__ gam, const float* __restrict__ bet,
    float* __restrict__ io){                   // d_out, write-only
  __shared__ unsigned short sW[73728];         // 147456 B
  int tid = threadIdx.x, blk = blockIdx.x;
  int bi = blk / (HW / 256);
  int pos0 = (blk - bi * (HW / 256)) * 256;
  #pragma unroll
  for (int it = 0; it < 18; ++it){
    int idx = it * 512 + tid;                  // 9216 uint4 chunks
    *(uint4*)&sW[idx * 8] = ((const uint4*)wP)[idx];
  }
  __syncthreads();

  int wv = tid >> 6, lane = tid & 63, r = lane & 15, g = lane >> 4;
  int pos = pos0 + wv * 32 + r;                // group m adds m*16
  size_t tok = (size_t)bi * HW + pos;

  // ---- load x2 frags + inline LN2 -> xn2 fragments xb[2][3] ----
  bf16x8 xb[2][3];
  #pragma unroll
  for (int m = 0; m < 2; ++m){
    bf16x8 xc[3];
    float xv[24];
    float sum = 0.f, sq = 0.f;
    #pragma unroll
    for (int ks = 0; ks < 3; ++ks){
      xc[ks] = *(const bf16x8*)(x2b + (tok + m * 16) * CB + ks * 32 + g * 8);
      #pragma unroll
      for (int e = 0; e < 8; ++e){
        float v = bf2f((unsigned short)xc[ks][e]);
        xv[ks * 8 + e] = v;
        sum += v; sq += v * v;
      }
    }
    sum += __shfl_xor(sum, 16); sq += __shfl_xor(sq, 16);
    sum += __shfl_xor(sum, 32); sq += __shfl_xor(sq, 32);
    float mean = sum * (1.f / 96.f);
    float var  = sq * (1.f / 96.f) - mean * mean;
    float rs = rsqrtf(var + 1e-5f);
    #pragma unroll
    for (int ks = 0; ks < 3; ++ks){
      float4 g0 = *(const float4*)&gam[ks * 32 + g * 8];
      float4 g1 = *(const float4*)&gam[ks * 32 + g * 8 + 4];
      float4 b0 = *(const float4*)&bet[ks * 32 + g * 8];
      float4 b1v = *(const float4*)&bet[ks * 32 + g * 8 + 4];
      float gg[8] = {g0.x,g0.y,g0.z,g0.w,g1.x,g1.y,g1.z,g1.w};
      float bb[8] = {b0.x,b0.y,b0.z,b0.w,b1v.x,b1v.y,b1v.z,b1v.w};
      unsigned pw[4];
      #pragma unroll
      for (int e2 = 0; e2 < 4; ++e2){
        float v0 = (xv[ks * 8 + 2*e2]   - mean) * rs * gg[2*e2]   + bb[2*e2];
        float v1 = (xv[ks * 8 + 2*e2+1] - mean) * rs * gg[2*e2+1] + bb[2*e2+1];
        pw[e2] = pack2(v0, v1);
      }
      union { unsigned u[4]; bf16x8 v; } u;
      u.u[0] = pw[0]; u.u[1] = pw[1]; u.u[2] = pw[2]; u.u[3] = pw[3];
      xb[m][ks] = u.v;
    }
  }

  // ---- streamed n-loop ----
  f32x4 acc2[2][6];
  #pragma unroll
  for (int m = 0; m < 2; ++m)
    #pragma unroll
    for (int co = 0; co < 6; ++co) acc2[m][co] = (f32x4){0.f,0.f,0.f,0.f};

  #pragma unroll
  for (int n = 0; n < 24; ++n){
    f32x4 acc0 = (f32x4){0.f,0.f,0.f,0.f};
    f32x4 acc1 = (f32x4){0.f,0.f,0.f,0.f};
    __builtin_amdgcn_s_setprio(1);
    #pragma unroll
    for (int ks = 0; ks < 3; ++ks){
      bf16x8 a = *(const bf16x8*)&sW[((n * 3 + ks) * 64 + lane) * 8];
      acc0 = MFMA32(a, xb[0][ks], acc0);
      acc1 = MFMA32(a, xb[1][ks], acc1);
    }
    __builtin_amdgcn_s_setprio(0);
    float4 bv = *(const float4*)&b1[n * 16 + 4 * g];
    union { unsigned u[2]; bf16x4 v; } u0, u1;
    u0.u[0] = pack2(gelu_sig(acc0[0] + bv.x), gelu_sig(acc0[1] + bv.y));
    u0.u[1] = pack2(gelu_sig(acc0[2] + bv.z), gelu_sig(acc0[3] + bv.w));
    u1.u[0] = pack2(gelu_sig(acc1[0] + bv.x), gelu_sig(acc1[1] + bv.y));
    u1.u[1] = pack2(gelu_sig(acc1[2] + bv.z), gelu_sig(acc1[3] + bv.w));
    bf16x4 h0 = u0.v, h1 = u1.v;
    __builtin_amdgcn_s_setprio(1);
    #pragma unroll
    for (int co = 0; co < 6; ++co){
      bf16x4 a2 = *(const bf16x4*)&sW[36864 + ((co * 24 + n) * 64 + lane) * 4];
      acc2[0][co] = MFMA16(a2, h0, acc2[0][co]);
      acc2[1][co] = MFMA16(a2, h1, acc2[1][co]);
    }
    __builtin_amdgcn_s_setprio(0);
  }
  // ---- epilogue: out = x2 + y + b2, write-only NCHW ----
  #pragma unroll
  for (int co = 0; co < 6; ++co){
    float4 bv = *(const float4*)&b2[co * 16 + 4 * g];
    float bb[4] = {bv.x, bv.y, bv.z, bv.w};
    #pragma unroll
    for (int i = 0; i < 4; ++i){
      int c = co * 16 + 4 * g + i;
      float* p0 = io + ((size_t)bi * CB + c) * HW + pos;
      #pragma unroll
      for (int m = 0; m < 2; ++m){
        float x2s = bf2f(x2b[(tok + m * 16) * CB + c]);
        p0[m * 16] = x2s + acc2[m][co][i] + bb[i];
      }
    }
  }
}

extern "C" void kernel_launch(void* const* d_in, const int* in_sizes, int n_in,
                              void* d_out, int out_size, void* d_ws, size_t ws_size,
                              hipStream_t stream){
  const float* x        = (const float*)d_in[0];
  const float* n1g      = (const float*)d_in[1];
  const float* n1b      = (const float*)d_in[2];
  const float* qkv_w    = (const float*)d_in[3];
  const float* qkv_b    = (const float*)d_in[4];
  const float* proj_w   = (const float*)d_in[5];
  const float* proj_b   = (const float*)d_in[6];
  const float* rel_bias = (const float*)d_in[7];
  const float* n2g      = (const float*)d_in[8];
  const float* n2b      = (const float*)d_in[9];
  const float* w1       = (const float*)d_in[10];
  const float* b1       = (const float*)d_in[11];
  const float* w2       = (const float*)d_in[12];
  const float* b2       = (const float*)d_in[13];
  const int* rel_index  = (const int*)d_in[14];
  float* outp = (float*)d_out;

  char* ws = (char*)d_ws;
  unsigned short* qkvT  = (unsigned short*)ws;            // 288x96 = 27648
  unsigned short* projT = qkvT + 288 * 96;                // 96x96 = 9216
  unsigned short* w1P   = projT + 96 * 96;                // packed 36864
  unsigned short* w2P   = w1P + 36864;                    // packed 36864
  float* biasT          = (float*)(ws + 221184);          // [3][16][64][4]
  unsigned short* xn    = (unsigned short*)(ws + 221184 + 49152);

  prep_all<<<dim3(480), 256, 0, stream>>>(qkv_w, proj_w, w1, w2, rel_bias,
                                          rel_index, qkvT, projT, w1P, w2P, biasT);

  ln_first  <<<dim3(NTOK / 64), 256, 0, stream>>>(x, n1g, n1b, xn);
  attn_fused<<<dim3(NWIN),      256, 0, stream>>>(xn, qkvT, qkv_b, biasT);
  proj_res  <<<dim3(NTOK / 64), 256, 0, stream>>>(xn, projT, proj_b, x);
  mlp_fused <<<dim3(NTOK / 256), 512, 0, stream>>>(xn, w1P, b1, b2, n2g, n2b, outp);
}